// Round 1
// baseline (164.558 us; speedup 1.0000x reference)
//
#include <hip/hip_runtime.h>

// Problem constants (B, T, D) from the reference.
#define BB 8
#define TT 512
#define DD 64

// One block per (b, i) row. Threads 0..63 first compute v[b,i,:] = x[b,i,:] @ W^T + bias
// into LDS (and stage x[b,i,:]). Then every thread owns j = tid and j = tid+256 and
// computes out[b,i,j] = sum_d softmax_d(-(xi-xj)^2) * v[b,i,d] with a fused
// numerator/denominator accumulation (K never materialized, no cross-lane reduction).
__global__ __launch_bounds__(256) void rbf_fused(
    const float* __restrict__ x,     // (B,T,D)
    const float* __restrict__ W,     // (D,D), v[.,e] = sum_d x[.,d]*W[e,d]
    const float* __restrict__ bias,  // (D,)
    float* __restrict__ out)         // (B,T,T)
{
    const int bi = blockIdx.x;       // b*T + i
    const int b  = bi >> 9;          // / TT
    const int t  = threadIdx.x;

    __shared__ float xi_s[DD];
    __shared__ float vi_s[DD];

    const float* xrow = x + (size_t)bi * DD;

    if (t < DD) {
        xi_s[t] = xrow[t];
        const float* wrow = W + (size_t)t * DD;
        float acc = bias[t];
        #pragma unroll
        for (int d = 0; d < DD; d += 4) {
            float4 xv = *reinterpret_cast<const float4*>(xrow + d);
            float4 wv = *reinterpret_cast<const float4*>(wrow + d);
            acc = fmaf(xv.x, wv.x, acc);
            acc = fmaf(xv.y, wv.y, acc);
            acc = fmaf(xv.z, wv.z, acc);
            acc = fmaf(xv.w, wv.w, acc);
        }
        vi_s[t] = acc;
    }
    __syncthreads();

    const float* xb   = x + (size_t)b * TT * DD;
    float*       orow = out + (size_t)bi * TT;

    #pragma unroll
    for (int jj = 0; jj < 2; ++jj) {
        const int j = t + jj * 256;
        const float* xj = xb + (size_t)j * DD;
        float num = 0.f, den = 0.f;
        #pragma unroll
        for (int d = 0; d < DD; d += 4) {
            float4 xjv = *reinterpret_cast<const float4*>(xj + d);
            float4 xiv = *reinterpret_cast<const float4*>(xi_s + d);
            float4 viv = *reinterpret_cast<const float4*>(vi_s + d);
            float d0 = xiv.x - xjv.x;
            float d1 = xiv.y - xjv.y;
            float d2 = xiv.z - xjv.z;
            float d3 = xiv.w - xjv.w;
            // softmax arg is -(diff^2) <= 0; row max ~ 0 for this data, so no
            // max-subtraction needed (exp can underflow to 0 harmlessly, never overflow).
            float e0 = __expf(-d0 * d0);
            float e1 = __expf(-d1 * d1);
            float e2 = __expf(-d2 * d2);
            float e3 = __expf(-d3 * d3);
            num = fmaf(e0, viv.x, num);
            num = fmaf(e1, viv.y, num);
            num = fmaf(e2, viv.z, num);
            num = fmaf(e3, viv.w, num);
            den += e0 + e1 + e2 + e3;
        }
        orow[j] = num / den;
    }
}

extern "C" void kernel_launch(void* const* d_in, const int* in_sizes, int n_in,
                              void* d_out, int out_size, void* d_ws, size_t ws_size,
                              hipStream_t stream) {
    const float* x    = (const float*)d_in[0];
    const float* W    = (const float*)d_in[1];
    const float* bias = (const float*)d_in[2];
    float* out        = (float*)d_out;

    rbf_fused<<<BB * TT, 256, 0, stream>>>(x, W, bias, out);
}

// Round 2
// 93.875 us; speedup vs baseline: 1.7530x; 1.7530x over previous
//
#include <hip/hip_runtime.h>

#define BB 8
#define TT 512
#define DD 64
#define IT 4      // i-rows per block (one per wave)
#define JT 64     // j-rows per LDS tile
#define LDP 65    // padded LDS stride: lane l -> bank (l + d) % 32, 2-way alias = free

__device__ __forceinline__ float fast_exp2(float v) {
#if __has_builtin(__builtin_amdgcn_exp2f)
    return __builtin_amdgcn_exp2f(v);
#else
    return exp2f(v);
#endif
}

// Block = 256 threads = 4 waves. Wave w owns row i = i0 + w (xi/vi wave-uniform).
// j handled in 8 tiles of 64 rows staged coalesced into padded LDS; lane l owns
// j_local = l. exp(-(d)^2) computed as exp2(-(d*S)^2) with S = sqrt(log2 e),
// applied once at staging time instead of per pair-element.
__global__ __launch_bounds__(256) void rbf_fused2(
    const float* __restrict__ x,     // (B,T,D)
    const float* __restrict__ W,     // (D,D)
    const float* __restrict__ bias,  // (D,)
    float* __restrict__ out)         // (B,T,T)
{
    const int blk = blockIdx.x;           // b*(T/IT) + itile
    const int b   = blk >> 7;             // / (512/4)
    const int i0  = (blk & 127) * IT;
    const int t   = threadIdx.x;
    const int w   = t >> 6;               // wave id == i_local
    const int l   = t & 63;               // lane

    __shared__ float xi_s[IT][DD];        // pre-scaled by S
    __shared__ float vi_s[IT][DD];
    __shared__ float xj_s[JT][LDP];       // pre-scaled by S

    const float S = 1.2011224087864498f;  // sqrt(log2(e))

    // ---- phase 1: v = x@W^T + b for the 4 i-rows; stage xi (scaled) ----
    const float* xrow = x + (size_t)(b * TT + i0 + w) * DD;
    {
        const float* wrow = W + (size_t)l * DD;
        float acc = bias[l];
        #pragma unroll
        for (int d = 0; d < DD; d += 4) {
            float4 xv = *reinterpret_cast<const float4*>(xrow + d);
            float4 wv = *reinterpret_cast<const float4*>(wrow + d);
            acc = fmaf(xv.x, wv.x, acc);
            acc = fmaf(xv.y, wv.y, acc);
            acc = fmaf(xv.z, wv.z, acc);
            acc = fmaf(xv.w, wv.w, acc);
        }
        vi_s[w][l] = acc;
        xi_s[w][l] = xrow[l] * S;
    }
    __syncthreads();

    // xi into registers (wave-uniform broadcast reads, done once)
    float4 xi_r[16];
    #pragma unroll
    for (int c = 0; c < 16; ++c)
        xi_r[c] = *reinterpret_cast<const float4*>(&xi_s[w][c * 4]);

    const float* xb   = x + (size_t)b * TT * DD;
    float*       orow = out + (size_t)(b * TT + i0 + w) * TT;

    for (int jt = 0; jt < TT / JT; ++jt) {
        if (jt) __syncthreads();          // readers of previous tile done
        // ---- stage xj tile, coalesced, scaled by S ----
        #pragma unroll
        for (int u = 0; u < 4; ++u) {
            int idx = u * 256 + t;        // float4 index within 64x64 tile
            int r = idx >> 4;
            int c = (idx & 15) * 4;
            float4 v = *reinterpret_cast<const float4*>(
                xb + (size_t)(jt * JT + r) * DD + c);
            xj_s[r][c + 0] = v.x * S;
            xj_s[r][c + 1] = v.y * S;
            xj_s[r][c + 2] = v.z * S;
            xj_s[r][c + 3] = v.w * S;
        }
        __syncthreads();

        // ---- fused softmax-dot for (i = i0+w, j = jt*64 + l) ----
        float num = 0.f, den = 0.f;
        #pragma unroll
        for (int c = 0; c < 16; ++c) {
            float4 xj = *reinterpret_cast<const float4*>(&xj_s[l][c * 4]);
            float4 vi = *reinterpret_cast<const float4*>(&vi_s[w][c * 4]);
            float4 xi = xi_r[c];
            float d0 = xi.x - xj.x;
            float d1 = xi.y - xj.y;
            float d2 = xi.z - xj.z;
            float d3 = xi.w - xj.w;
            float e0 = fast_exp2(-(d0 * d0));
            float e1 = fast_exp2(-(d1 * d1));
            float e2 = fast_exp2(-(d2 * d2));
            float e3 = fast_exp2(-(d3 * d3));
            num = fmaf(e0, vi.x, num);
            num = fmaf(e1, vi.y, num);
            num = fmaf(e2, vi.z, num);
            num = fmaf(e3, vi.w, num);
            den += (e0 + e1) + (e2 + e3);
        }
        orow[jt * JT + l] = num / den;
    }
}

extern "C" void kernel_launch(void* const* d_in, const int* in_sizes, int n_in,
                              void* d_out, int out_size, void* d_ws, size_t ws_size,
                              hipStream_t stream) {
    const float* x    = (const float*)d_in[0];
    const float* W    = (const float*)d_in[1];
    const float* bias = (const float*)d_in[2];
    float* out        = (float*)d_out;

    rbf_fused2<<<BB * (TT / IT), 256, 0, stream>>>(x, W, bias, out);
}

// Round 3
// 91.364 us; speedup vs baseline: 1.8011x; 1.0275x over previous
//
#include <hip/hip_runtime.h>

#define BB 8
#define TT 512
#define DD 64
#define IT 4            // i-rows per block, one per wave
#define JTILE 64        // j-rows per LDS tile
#define NTILE 4         // tiles per block (block owns a 256-j half)
#define GR 17           // float4-granules per padded LDS row (16 data + 1 pad)
#define S_SCALE 1.2011224087864498f   // sqrt(log2(e)); exp(-(u)^2) = exp2(-(S*u)^2)

__device__ __forceinline__ float fast_exp2(float v) {
#if __has_builtin(__builtin_amdgcn_exp2f)
    return __builtin_amdgcn_exp2f(v);
#else
    return exp2f(v);
#endif
}
__device__ __forceinline__ float fast_rcp(float v) {
#if __has_builtin(__builtin_amdgcn_rcpf)
    return __builtin_amdgcn_rcpf(v);
#else
    return 1.0f / v;
#endif
}
// wave-uniform value -> SGPR (compiler keeps it scalar)
__device__ __forceinline__ float bcast0(float v) {
    return __int_as_float(__builtin_amdgcn_readfirstlane(__float_as_int(v)));
}

// Block = 4 waves; wave w owns row i = itile*4 + w. Block owns j-half (256 j)
// processed as 4 LDS tiles of 64 rows, double-buffered (1 barrier/tile).
// vi in VGPRs, xi (scaled) in SGPRs, xj (scaled) in padded LDS -> the only
// steady-state LDS traffic is 16 conflict-free ds_read_b128 per output.
__global__ __launch_bounds__(256, 4) void rbf_fused3(
    const float* __restrict__ x,     // (B,T,D)
    const float* __restrict__ W,     // (D,D)
    const float* __restrict__ bias,  // (D,)
    float* __restrict__ out)         // (B,T,T)
{
    const int blk = blockIdx.x;      // ((b*128 + itile)*2 + jh)
    const int jh  = blk & 1;
    const int it  = (blk >> 1) & 127;
    const int b   = blk >> 8;
    const int t   = threadIdx.x;
    const int w   = t >> 6;
    const int l   = t & 63;

    __shared__ float xi_s[IT][DD];                  // scaled by S
    __shared__ float vi_s[IT][DD];
    __shared__ float xj_s[2][JTILE * GR * 4];       // scaled by S, granule-padded

    // ---- phase 1: v = x@W^T + b for the 4 i-rows; stage xi*S ----
    const float* xrow = x + (size_t)(b * TT + it * IT + w) * DD;
    {
        const float* wr = W + (size_t)l * DD;
        float acc = bias[l];
        #pragma unroll
        for (int d = 0; d < DD; d += 4) {
            float4 xv = *(const float4*)(xrow + d);
            float4 wv = *(const float4*)(wr + d);
            acc = fmaf(xv.x, wv.x, acc); acc = fmaf(xv.y, wv.y, acc);
            acc = fmaf(xv.z, wv.z, acc); acc = fmaf(xv.w, wv.w, acc);
        }
        vi_s[w][l] = acc;
        xi_s[w][l] = xrow[l] * S_SCALE;
    }
    __syncthreads();

    // vi -> VGPRs (held across all tiles); xi -> SGPRs via readfirstlane
    float4 vi_r[16];
    float  sxi[DD];
    #pragma unroll
    for (int c = 0; c < 16; ++c) {
        vi_r[c] = *(const float4*)(&vi_s[w][c * 4]);
        float4 xv = *(const float4*)(&xi_s[w][c * 4]);
        sxi[c * 4 + 0] = bcast0(xv.x);
        sxi[c * 4 + 1] = bcast0(xv.y);
        sxi[c * 4 + 2] = bcast0(xv.z);
        sxi[c * 4 + 3] = bcast0(xv.w);
    }

    const float* xb = x + ((size_t)b * TT + (size_t)jh * 256) * DD;
    float* orow = out + (size_t)(b * TT + it * IT + w) * TT + jh * 256;

    // staging map: thread covers granules g = u*256 + t: row = g>>4, col = g&15
    const int sr = t >> 4;
    const int sc = t & 15;
    float4 pf[4];

    // prefetch + stage tile 0
    #pragma unroll
    for (int u = 0; u < 4; ++u)
        pf[u] = *(const float4*)(xb + (size_t)(u * 16 + sr) * DD + sc * 4);
    {
        float4* dst = (float4*)xj_s[0];
        #pragma unroll
        for (int u = 0; u < 4; ++u) {
            float4 v = pf[u];
            v.x *= S_SCALE; v.y *= S_SCALE; v.z *= S_SCALE; v.w *= S_SCALE;
            dst[(u * 16 + sr) * GR + sc] = v;
        }
    }
    __syncthreads();

    int buf = 0;
    for (int jt = 0; jt < NTILE; ++jt) {
        // prefetch next tile into registers (covers L2 latency with compute)
        if (jt + 1 < NTILE) {
            #pragma unroll
            for (int u = 0; u < 4; ++u)
                pf[u] = *(const float4*)(
                    xb + (size_t)((jt + 1) * JTILE + u * 16 + sr) * DD + sc * 4);
        }

        // ---- fused softmax-dot: i = wave's row, j = jt*64 + l ----
        const float4* xjs = (const float4*)xj_s[buf];
        float num = 0.f, den = 0.f;
        #pragma unroll
        for (int cc = 0; cc < 16; ++cc) {
            float4 xj = xjs[l * GR + cc];       // conflict-free: bank 4(l+cc)%32
            float4 vi = vi_r[cc];
            float d0 = sxi[cc * 4 + 0] - xj.x;
            float d1 = sxi[cc * 4 + 1] - xj.y;
            float d2 = sxi[cc * 4 + 2] - xj.z;
            float d3 = sxi[cc * 4 + 3] - xj.w;
            float e0 = fast_exp2(-(d0 * d0));
            float e1 = fast_exp2(-(d1 * d1));
            float e2 = fast_exp2(-(d2 * d2));
            float e3 = fast_exp2(-(d3 * d3));
            num = fmaf(e0, vi.x, num);
            num = fmaf(e1, vi.y, num);
            num = fmaf(e2, vi.z, num);
            num = fmaf(e3, vi.w, num);
            den += (e0 + e1) + (e2 + e3);
        }
        orow[jt * JTILE + l] = num * fast_rcp(den);

        // stage prefetched tile into the other buffer
        if (jt + 1 < NTILE) {
            float4* dst = (float4*)xj_s[buf ^ 1];
            #pragma unroll
            for (int u = 0; u < 4; ++u) {
                float4 v = pf[u];
                v.x *= S_SCALE; v.y *= S_SCALE; v.z *= S_SCALE; v.w *= S_SCALE;
                dst[(u * 16 + sr) * GR + sc] = v;
            }
            __syncthreads();
            buf ^= 1;
        }
    }
}

extern "C" void kernel_launch(void* const* d_in, const int* in_sizes, int n_in,
                              void* d_out, int out_size, void* d_ws, size_t ws_size,
                              hipStream_t stream) {
    const float* x    = (const float*)d_in[0];
    const float* W    = (const float*)d_in[1];
    const float* bias = (const float*)d_in[2];
    float* out        = (float*)d_out;

    rbf_fused3<<<BB * (TT / IT) * 2, 256, 0, stream>>>(x, W, bias, out);
}